// Round 13
// baseline (2372.952 us; speedup 1.0000x reference)
//
#include <hip/hip_runtime.h>

#define N_    128
#define T_    64
#define D_    512
#define H_    1280
#define FOURH 5120
#define K3    1792                 // h(1280) + x(512)
#define COLS  160                  // gate-cols per strip (40 q x 4 gates)
#define ACCS  165                  // padded acclds row stride (f32)
#define GLP   2568                 // padded glds sample stride (halfs): word stride ≡ 4 mod 32
#define NB    256                  // 32 strips x 8 rh
#define SPB   16                   // samples per block
#define SCALE 0.02795084971874737f // 1/sqrt(1280)

typedef _Float16 half8 __attribute__((ext_vector_type(8)));
typedef _Float16 half2_t __attribute__((ext_vector_type(2)));
typedef float    f32x4 __attribute__((ext_vector_type(4)));
typedef unsigned u32x4 __attribute__((ext_vector_type(4)));

__device__ __forceinline__ float sigf(float x) { return 1.0f / (1.0f + __expf(-x)); }
__device__ __forceinline__ float tanhfast(float x) { return 1.0f - 2.0f / (1.0f + __expf(2.0f * x)); }

__device__ __forceinline__ void sc_load_u4(u32x4& d, const void* p) {
  asm volatile("global_load_dwordx4 %0, %1, off sc0 sc1" : "=v"(d) : "v"(p));
}
__device__ __forceinline__ void sc_store_u4(void* p, u32x4 d) {
  asm volatile("global_store_dwordx4 %0, %1, off sc0 sc1" :: "v"(p), "v"(d) : "memory");
}
__device__ __forceinline__ void sc_store_u1(void* p, unsigned d) {
  asm volatile("global_store_dword %0, %1, off sc0 sc1" :: "v"(p), "v"(d) : "memory");
}
__device__ __forceinline__ void vm_wait0() { asm volatile("s_waitcnt vmcnt(0)" ::: "memory"); }

// fence-free grid barrier; release = vm_wait0 (drains sc-stores + atomics to MALL)
__device__ __forceinline__ void gbar(unsigned* bar, unsigned target) {
  vm_wait0();
  __syncthreads();
  if (threadIdx.x == 0) {
    __hip_atomic_fetch_add(bar, 1u, __ATOMIC_RELAXED, __HIP_MEMORY_SCOPE_AGENT);
    int guard = 0;
    while (__hip_atomic_load(bar, __ATOMIC_RELAXED, __HIP_MEMORY_SCOPE_AGENT) < target &&
           ++guard < (1 << 20))
      __builtin_amdgcn_s_sleep(2);
  }
  __syncthreads();
}

// ---------------- one-time prep ----------------

// W (K x 5120 f32) -> out[colp][K] fp16. colp = (hh/40)*160 + (hh%40)*4 + g
__global__ __launch_bounds__(256) void trans_w(const float* __restrict__ W,
                                               _Float16* __restrict__ out,
                                               int ostride, int koff) {
  __shared__ float tile[256][33];
  int c0 = blockIdx.x * 32, k0 = blockIdx.y * 256;
  int tx = threadIdx.x & 31, ty = threadIdx.x >> 5;
#pragma unroll
  for (int i = 0; i < 32; ++i)
    tile[ty + i * 8][tx] = W[(size_t)(k0 + ty + i * 8) * FOURH + c0 + tx];
  __syncthreads();
  int c = c0 + tx, g = c / H_, hh = c % H_;
  int colp = (hh / 40) * COLS + (hh % 40) * 4 + g;
  _Float16* dst = out + (size_t)colp * ostride + koff + k0 + ty * 32;
#pragma unroll
  for (int i8 = 0; i8 < 4; ++i8) {
    half8 v;
#pragma unroll
    for (int j = 0; j < 8; ++j) v[j] = (_Float16)tile[ty * 32 + i8 * 8 + j][tx];
    *(half8*)(dst + i8 * 8) = v;
  }
}

__global__ __launch_bounds__(256) void cvt_f16(const float* __restrict__ src,
                                               _Float16* __restrict__ dst, int n) {
  for (int i = blockIdx.x * blockDim.x + threadIdx.x; i < n; i += gridDim.x * blockDim.x)
    dst[i] = (_Float16)src[i];
}

// A (N,H,16 f32) -> AfT [n][l][h] fp16 (for gemm_G) and Af16 [n][h][l] fp16 (epilogue)
__global__ __launch_bounds__(256) void prep_af(const float* __restrict__ A,
                                               _Float16* __restrict__ AfT,
                                               _Float16* __restrict__ Af16) {
  __shared__ float tile[16][17];
  int n = blockIdx.x;
  int tl = threadIdx.x & 15, th = threadIdx.x >> 4;
  for (int hb = 0; hb < H_; hb += 16) {
    float v = A[((size_t)n * H_ + hb + th) * 16 + tl];
    Af16[((size_t)n * H_ + hb + th) * 16 + tl] = (_Float16)v;
    tile[th][tl] = v;
    __syncthreads();
    AfT[((size_t)n * 16 + th) * H_ + hb + tl] = (_Float16)tile[tl][th];
    __syncthreads();
  }
}

__global__ void prep_b(const float* __restrict__ b, float* __restrict__ bp) {
  int c = blockIdx.x * 256 + threadIdx.x;
  if (c < FOURH) {
    int g = c / H_, hh = c % H_;
    bp[(hh / 40) * COLS + (hh % 40) * 4 + g] = b[c];
  }
}

// G[n][colp][l] = sum_k Wattn[k][colp] * Af[n][k][l]
__global__ __launch_bounds__(256) void gemm_G(const _Float16* __restrict__ WaT,
                                              const _Float16* __restrict__ AfT,
                                              _Float16* __restrict__ G) {
  int cb = blockIdx.x;
  int wv = threadIdx.x >> 6, lane = threadIdx.x & 63, lr = lane & 15, lkg = lane >> 4;
  const _Float16* Ab = WaT + ((size_t)(cb * 128 + wv * 32 + lr)) * H_ + lkg * 8;
  for (int i = 0; i < 8; ++i) {
    int n = blockIdx.y * 8 + i;
    const _Float16* Bb = AfT + ((size_t)n * 16 + lr) * H_ + lkg * 8;
    f32x4 acc0 = (f32x4){0, 0, 0, 0}, acc1 = (f32x4){0, 0, 0, 0};
    for (int kk = 0; kk < H_; kk += 32) {
      half8 b = *(const half8*)(Bb + kk);
      half8 a0 = *(const half8*)(Ab + kk);
      half8 a1 = *(const half8*)(Ab + (size_t)16 * H_ + kk);
      acc0 = __builtin_amdgcn_mfma_f32_16x16x32_f16(a0, b, acc0, 0, 0, 0);
      acc1 = __builtin_amdgcn_mfma_f32_16x16x32_f16(a1, b, acc1, 0, 0, 0);
    }
#pragma unroll
    for (int j = 0; j < 4; ++j) {
      G[((size_t)n * FOURH + cb * 128 + wv * 32 + lkg * 4 + j) * 16 + lr] = (_Float16)acc0[j];
      G[((size_t)n * FOURH + cb * 128 + wv * 32 + 16 + lkg * 4 + j) * 16 + lr] = (_Float16)acc1[j];
    }
  }
}

// ---------------- sequential recurrence: 256 blocks x 640 threads, 1 barrier/step ----------------
// r9-proven body + (1) nt stores for out, (2) nt loads for x16, (3) glds stride pad 2560->2568.
__global__ __launch_bounds__(640, 3) void seq_kernel(
    const _Float16* __restrict__ Wt, const _Float16* __restrict__ G,
    const float* __restrict__ Afull, const _Float16* __restrict__ Af16,
    const _Float16* __restrict__ x16, const float* __restrict__ bp,
    _Float16* __restrict__ hbuf, float* __restrict__ S,
    float* __restrict__ out, unsigned* __restrict__ bar) {
  __shared__ _Float16 blds[SPB * K3];        // 57,344 B (aliased as acc f32[16][ACCS] post-GEMM)
  __shared__ _Float16 glds[SPB * GLP];       // 82,176 B (G slice; padded stride: 8-way not 64-way)
  __shared__ _Float16 htr[SPB][40];          //  1,280 B
  __shared__ float sred[10][16][17];         // 10,880 B
  __shared__ float sc_s[16][16];             //  1,024 B
  float* acclds = (float*)blds;

  const int bid = blockIdx.x, tid = threadIdx.x;
  const int li = (bid & 7) * 32 + (bid >> 3);   // cluster strips per XCD
  const int s = li >> 3, rh = li & 7, n0 = rh * SPB;
  const int w = tid >> 6, lane = tid & 63;
  const int lr = lane & 15, lkg = lane >> 4, lkg8 = lkg * 8;
  const int bswz = (lr & 7) * 8;
  const int en = tid & 15, eq = tid >> 4;       // epilogue: thread owns (sample en, q eq)
  const int ehidx = s * 40 + eq;
  const int emyn = n0 + en;

  // ---- G slice -> LDS once (step-invariant): 16n x 160colp x 16l, padded stride ----
#pragma unroll
  for (int j = 0; j < 8; ++j) {
    int id = tid + j * 640;
    if (id < 5120) {
      int n = id / 320, r = id % 320;
      *(u32x4*)&glds[n * GLP + r * 8] =
          *(const u32x4*)(G + ((size_t)(n0 + n) * FOURH + s * COLS) * 16 + r * 8);
    }
  }

  const _Float16* Ap = Wt + (size_t)(s * COLS + w * 16 + lr) * K3 + lkg8;
  float c_reg;

  // ---- init: h0 = mean_l Af, c0 = h0, scores for step 0 ----
  {
    const f32x4* afp = (const f32x4*)(Afull + ((size_t)emyn * H_ + ehidx) * 16);
    f32x4 a0 = afp[0], a1 = afp[1], a2 = afp[2], a3 = afp[3];
    float sum = 0.f;
#pragma unroll
    for (int j = 0; j < 4; ++j) sum += a0[j] + a1[j] + a2[j] + a3[j];
    float h0 = sum * 0.0625f;
    c_reg = h0;
    htr[en][eq] = (_Float16)h0;
    float pl[16];
#pragma unroll
    for (int j = 0; j < 4; ++j) {
      pl[j] = h0 * a0[j]; pl[4 + j] = h0 * a1[j];
      pl[8 + j] = h0 * a2[j]; pl[12 + j] = h0 * a3[j];
    }
#pragma unroll
    for (int l = 0; l < 16; ++l) {
      pl[l] += __shfl_xor(pl[l], 16);
      pl[l] += __shfl_xor(pl[l], 32);
    }
    if (lane < 16) {
#pragma unroll
      for (int l = 0; l < 16; ++l) sred[w][lane][l] = pl[l];
    }
    __syncthreads();
    if (tid < 256) {
      int n = tid >> 4, l = tid & 15;
      float v = 0.f;
#pragma unroll
      for (int ww = 0; ww < 10; ++ww) v += sred[ww][n][l];
      __hip_atomic_fetch_add(S + (size_t)(n0 + n) * 16 + l, v,
                             __ATOMIC_RELAXED, __HIP_MEMORY_SCOPE_AGENT);
    }
    if (tid < 80) {
      int n = tid / 5, ch = tid % 5;
      u32x4 v = *(const u32x4*)&htr[n][ch * 8];
      sc_store_u4(hbuf + (size_t)(n0 + n) * H_ + s * 40 + ch * 8, v);
    }
    gbar(bar, NB);
  }

  for (int t = 0; t < T_; ++t) {
    const int par = t & 1;
    // ---- stage h (sc) + x_t (nt) -> LDS; scores (sc) via LDS ----
    const _Float16* hsrc = hbuf + ((size_t)par * N_ + n0) * H_;
    u32x4 hv[4];
#pragma unroll
    for (int j = 0; j < 4; ++j) sc_load_u4(hv[j], hsrc + (tid + j * 640) * 8);
    u32x4 svr;
    if (tid < 64)
      sc_load_u4(svr, S + (size_t)(t % 3) * 2048 + (size_t)(n0 + (tid >> 2)) * 16 + (tid & 3) * 4);
    half8 xh[2];
#pragma unroll
    for (int j = 0; j < 2; ++j) {
      int id = tid + j * 640;
      if (id < 1024)
        xh[j] = __builtin_nontemporal_load(
            (const half8*)(x16 + ((size_t)(n0 + (id >> 6)) * T_ + t) * D_ + (id & 63) * 8));
    }
    vm_wait0();
    __builtin_amdgcn_sched_barrier(0);
#pragma unroll
    for (int j = 0; j < 4; ++j) {
      int i = tid + j * 640;
      int n_l = i / 160, c8 = i % 160;
      *(u32x4*)&blds[((size_t)n_l * 224 + (c8 ^ (n_l & 7))) * 8] = hv[j];
    }
#pragma unroll
    for (int j = 0; j < 2; ++j) {
      int id = tid + j * 640;
      if (id < 1024) {
        int xn = id >> 6, c8 = 160 + (id & 63);
        *(half8*)&blds[((size_t)xn * 224 + (c8 ^ (xn & 7))) * 8] = xh[j];
      }
    }
    if (tid < 64) *(u32x4*)&sc_s[tid >> 2][(tid & 3) * 4] = svr;
    __syncthreads();

    // softmax for this thread's sample
    float wgt[16], m = -1e30f;
#pragma unroll
    for (int l = 0; l < 16; ++l) { wgt[l] = sc_s[en][l] * SCALE; m = fmaxf(m, wgt[l]); }
    float ssum = 0.f;
#pragma unroll
    for (int l = 0; l < 16; ++l) { wgt[l] = __expf(wgt[l] - m); ssum += wgt[l]; }
    float inv = 1.0f / ssum;
    half2_t wh[8];
#pragma unroll
    for (int i = 0; i < 8; ++i) {
      wh[i][0] = (_Float16)(wgt[2 * i] * inv);
      wh[i][1] = (_Float16)(wgt[2 * i + 1] * inv);
    }

    // ---- GEMM: wave w owns 16 cols; depth-8 A double-buffer from L2-resident W ----
    f32x4 acc = (f32x4){0, 0, 0, 0};
    {
      half8 a0[4], a1[4];
#pragma unroll
      for (int j = 0; j < 4; ++j) a0[j] = *(const half8*)(Ap + j * 32);
#pragma unroll
      for (int rep = 0; rep < 6; ++rep) {
        const int base = rep * 256;
#pragma unroll
        for (int j = 0; j < 4; ++j) a1[j] = *(const half8*)(Ap + base + 128 + j * 32);
#pragma unroll
        for (int j = 0; j < 4; ++j) {
          half8 bf = *(const half8*)&blds[(size_t)lr * K3 + ((base + j * 32 + lkg8) ^ bswz)];
          acc = __builtin_amdgcn_mfma_f32_16x16x32_f16(a0[j], bf, acc, 0, 0, 0);
        }
#pragma unroll
        for (int j = 0; j < 4; ++j) a0[j] = *(const half8*)(Ap + base + 256 + j * 32);
#pragma unroll
        for (int j = 0; j < 4; ++j) {
          half8 bf = *(const half8*)&blds[(size_t)lr * K3 + ((base + 128 + j * 32 + lkg8) ^ bswz)];
          acc = __builtin_amdgcn_mfma_f32_16x16x32_f16(a1[j], bf, acc, 0, 0, 0);
        }
      }
#pragma unroll
      for (int j = 0; j < 4; ++j) a1[j] = *(const half8*)(Ap + 1664 + j * 32);
#pragma unroll
      for (int j = 0; j < 4; ++j) {
        half8 bf = *(const half8*)&blds[(size_t)lr * K3 + ((1536 + j * 32 + lkg8) ^ bswz)];
        acc = __builtin_amdgcn_mfma_f32_16x16x32_f16(a0[j], bf, acc, 0, 0, 0);
      }
#pragma unroll
      for (int j = 0; j < 4; ++j) {
        half8 bf = *(const half8*)&blds[(size_t)lr * K3 + ((1664 + j * 32 + lkg8) ^ bswz)];
        acc = __builtin_amdgcn_mfma_f32_16x16x32_f16(a1[j], bf, acc, 0, 0, 0);
      }
    }
    __syncthreads();                       // B consumed; alias blds as acc transpose
    // D[row=(lkg*4+j)=gatecol_local, col=lr=sample] -> acclds[sample][gatecol]
#pragma unroll
    for (int j = 0; j < 4; ++j)
      acclds[lr * ACCS + w * 16 + lkg * 4 + j] = acc[j];
    __syncthreads();

    // ---- epilogue: thread (en, eq) -> 4 gates, c/h update, out, score partials ----
    {
      const float* av4 = acclds + en * ACCS + eq * 4;
      const unsigned* gp32 = (const unsigned*)(glds + en * GLP + eq * 64);
      f32x4 bb = *(const f32x4*)(bp + s * COLS + eq * 4);
      float av[4];
#pragma unroll
      for (int g4 = 0; g4 < 4; ++g4) {
        float gd = 0.f;
#pragma unroll
        for (int i = 0; i < 8; ++i)
          gd = __builtin_amdgcn_fdot2(__builtin_bit_cast(half2_t, gp32[g4 * 8 + i]), wh[i], gd, false);
        av[g4] = av4[g4] + gd + bb[g4];
      }
      float cn = sigf(av[1]) * c_reg + sigf(av[0]) * tanhfast(av[3]);
      c_reg = cn;
      float hn = sigf(av[2]) * tanhfast(cn);
      __builtin_nontemporal_store(hn, &out[((size_t)emyn * T_ + t) * H_ + ehidx]);

      if (t < T_ - 1) {
        const half8* af8 = (const half8*)(Af16 + ((size_t)emyn * H_ + ehidx) * 16);
        half8 v0 = af8[0], v1 = af8[1];
        float pl[16];
#pragma unroll
        for (int l = 0; l < 8; ++l) { pl[l] = hn * (float)v0[l]; pl[8 + l] = hn * (float)v1[l]; }
        htr[en][eq] = (_Float16)hn;
#pragma unroll
        for (int l = 0; l < 16; ++l) {
          pl[l] += __shfl_xor(pl[l], 16);
          pl[l] += __shfl_xor(pl[l], 32);
        }
        if (lane < 16) {
#pragma unroll
          for (int l = 0; l < 16; ++l) sred[w][lane][l] = pl[l];
        }
        __syncthreads();
        if (tid < 256) {
          int n = tid >> 4, l = tid & 15;
          float v = 0.f;
#pragma unroll
          for (int ww = 0; ww < 10; ++ww) v += sred[ww][n][l];
          __hip_atomic_fetch_add(S + (size_t)((t + 1) % 3) * 2048 + (size_t)(n0 + n) * 16 + l, v,
                                 __ATOMIC_RELAXED, __HIP_MEMORY_SCOPE_AGENT);
        }
        if (bid < 64 && tid < 32)   // zero exactly 2048 words of S[(t+2)%3]
          sc_store_u1((unsigned*)(S + (size_t)((t + 2) % 3) * 2048) + bid * 32 + tid, 0u);
        if (tid < 80) {
          int n = tid / 5, ch = tid % 5;
          u32x4 v = *(const u32x4*)&htr[n][ch * 8];
          sc_store_u4(hbuf + ((size_t)((par ^ 1) * N_) + n0 + n) * H_ + s * 40 + ch * 8, v);
        }
        gbar(bar, (unsigned)(t + 2) * NB);
      }
    }
  }
}

// ---------------- launch ----------------
extern "C" void kernel_launch(void* const* d_in, const int* in_sizes, int n_in,
                              void* d_out, int out_size, void* d_ws, size_t ws_size,
                              hipStream_t stream) {
  const float* x  = (const float*)d_in[0];
  const float* A  = (const float*)d_in[1];
  const float* Wx = (const float*)d_in[2];
  const float* Wh = (const float*)d_in[3];
  const float* Wa = (const float*)d_in[4];
  const float* b  = (const float*)d_in[5];
  float* out = (float*)d_out;
  char* ws = (char*)d_ws;

  _Float16* Xreg = (_Float16*)(ws);                 // 18,350,080 (WaT then WcatT)
  _Float16* x16r = (_Float16*)(ws + 18350080);      //  8,388,608 (first holds AfT 5,242,880)
  _Float16* G    = (_Float16*)(ws + 26738688);      // 20,971,520
  _Float16* Af16 = (_Float16*)(ws + 47710208);      //  5,242,880
  _Float16* hbuf = (_Float16*)(ws + 52953088);      //    655,360
  float*    S    = (float*)(ws + 53608448);         //     24,576
  unsigned* bar  = (unsigned*)(ws + 53633024);      //         64
  float*    bpm  = (float*)(ws + 53633088);         //     20,480  -> total 53.65 MB

  (void)hipMemsetAsync(S, 0, 24576 + 64, stream);   // S + bar
  // phase 1: WaT into Xreg; AfT into x16 region; G = Af^T @ Wattn
  trans_w<<<dim3(160, 5), 256, 0, stream>>>(Wa, Xreg, H_, 0);
  prep_af<<<N_, 256, 0, stream>>>(A, x16r, Af16);
  gemm_G<<<dim3(40, 16), 256, 0, stream>>>(Xreg, x16r, G);
  // phase 2: overwrite Xreg with WcatT = [Wh; Wx]; overwrite AfT region with x16
  trans_w<<<dim3(160, 5), 256, 0, stream>>>(Wh, Xreg, K3, 0);
  trans_w<<<dim3(160, 2), 256, 0, stream>>>(Wx, Xreg, K3, H_);
  cvt_f16<<<2048, 256, 0, stream>>>(x, x16r, N_ * T_ * D_);
  prep_b<<<20, 256, 0, stream>>>(b, bpm);

  seq_kernel<<<dim3(NB), dim3(640), 0, stream>>>(Xreg, G, A, Af16, x16r, bpm, hbuf, S, out, bar);
}

// Round 14
// 2030.813 us; speedup vs baseline: 1.1685x; 1.1685x over previous
//
#include <hip/hip_runtime.h>

#define N_    128
#define T_    64
#define D_    512
#define H_    1280
#define FOURH 5120
#define K3    1792                 // h(1280) + x(512)
#define COLS  160                  // gate-cols per strip (40 q x 4 gates)
#define ACCS  165                  // padded acclds row stride (f32)
#define GLP   2568                 // padded glds sample stride (halfs)
#define NB    256                  // 32 strips x 8 rh groups
#define GRP   32                   // blocks per rh group (barrier scope)
#define SPB   16                   // samples per block
#define SCALE 0.02795084971874737f // 1/sqrt(1280)

typedef _Float16 half8 __attribute__((ext_vector_type(8)));
typedef _Float16 half2_t __attribute__((ext_vector_type(2)));
typedef float    f32x4 __attribute__((ext_vector_type(4)));
typedef unsigned u32x4 __attribute__((ext_vector_type(4)));

__device__ __forceinline__ float sigf(float x) { return 1.0f / (1.0f + __expf(-x)); }
__device__ __forceinline__ float tanhfast(float x) { return 1.0f - 2.0f / (1.0f + __expf(2.0f * x)); }

__device__ __forceinline__ void sc_load_u4(u32x4& d, const void* p) {
  asm volatile("global_load_dwordx4 %0, %1, off sc0 sc1" : "=v"(d) : "v"(p));
}
__device__ __forceinline__ void sc_store_u4(void* p, u32x4 d) {
  asm volatile("global_store_dwordx4 %0, %1, off sc0 sc1" :: "v"(p), "v"(d) : "memory");
}
__device__ __forceinline__ void sc_store_u1(void* p, unsigned d) {
  asm volatile("global_store_dword %0, %1, off sc0 sc1" :: "v"(p), "v"(d) : "memory");
}
__device__ __forceinline__ void vm_wait0() { asm volatile("s_waitcnt vmcnt(0)" ::: "memory"); }

// per-GROUP grid barrier (32 blocks sharing one rh sample-group); release = vm_wait0
__device__ __forceinline__ void gbar(unsigned* bar, unsigned target) {
  vm_wait0();
  __syncthreads();
  if (threadIdx.x == 0) {
    __hip_atomic_fetch_add(bar, 1u, __ATOMIC_RELAXED, __HIP_MEMORY_SCOPE_AGENT);
    int guard = 0;
    while (__hip_atomic_load(bar, __ATOMIC_RELAXED, __HIP_MEMORY_SCOPE_AGENT) < target &&
           ++guard < (1 << 20))
      __builtin_amdgcn_s_sleep(2);
  }
  __syncthreads();
}

// ---------------- one-time prep ----------------

// W (K x 5120 f32) -> out[colp][K] fp16. colp = (hh/40)*160 + (hh%40)*4 + g
__global__ __launch_bounds__(256) void trans_w(const float* __restrict__ W,
                                               _Float16* __restrict__ out,
                                               int ostride, int koff) {
  __shared__ float tile[256][33];
  int c0 = blockIdx.x * 32, k0 = blockIdx.y * 256;
  int tx = threadIdx.x & 31, ty = threadIdx.x >> 5;
#pragma unroll
  for (int i = 0; i < 32; ++i)
    tile[ty + i * 8][tx] = W[(size_t)(k0 + ty + i * 8) * FOURH + c0 + tx];
  __syncthreads();
  int c = c0 + tx, g = c / H_, hh = c % H_;
  int colp = (hh / 40) * COLS + (hh % 40) * 4 + g;
  _Float16* dst = out + (size_t)colp * ostride + koff + k0 + ty * 32;
#pragma unroll
  for (int i8 = 0; i8 < 4; ++i8) {
    half8 v;
#pragma unroll
    for (int j = 0; j < 8; ++j) v[j] = (_Float16)tile[ty * 32 + i8 * 8 + j][tx];
    *(half8*)(dst + i8 * 8) = v;
  }
}

__global__ __launch_bounds__(256) void cvt_f16(const float* __restrict__ src,
                                               _Float16* __restrict__ dst, int n) {
  for (int i = blockIdx.x * blockDim.x + threadIdx.x; i < n; i += gridDim.x * blockDim.x)
    dst[i] = (_Float16)src[i];
}

// A (N,H,16 f32) -> AfT [n][l][h] fp16 (for gemm_G) and Af16 [n][h][l] fp16 (epilogue)
__global__ __launch_bounds__(256) void prep_af(const float* __restrict__ A,
                                               _Float16* __restrict__ AfT,
                                               _Float16* __restrict__ Af16) {
  __shared__ float tile[16][17];
  int n = blockIdx.x;
  int tl = threadIdx.x & 15, th = threadIdx.x >> 4;
  for (int hb = 0; hb < H_; hb += 16) {
    float v = A[((size_t)n * H_ + hb + th) * 16 + tl];
    Af16[((size_t)n * H_ + hb + th) * 16 + tl] = (_Float16)v;
    tile[th][tl] = v;
    __syncthreads();
    AfT[((size_t)n * 16 + th) * H_ + hb + tl] = (_Float16)tile[tl][th];
    __syncthreads();
  }
}

__global__ void prep_b(const float* __restrict__ b, float* __restrict__ bp) {
  int c = blockIdx.x * 256 + threadIdx.x;
  if (c < FOURH) {
    int g = c / H_, hh = c % H_;
    bp[(hh / 40) * COLS + (hh % 40) * 4 + g] = b[c];
  }
}

// G[n][colp][l] = sum_k Wattn[k][colp] * Af[n][k][l]
__global__ __launch_bounds__(256) void gemm_G(const _Float16* __restrict__ WaT,
                                              const _Float16* __restrict__ AfT,
                                              _Float16* __restrict__ G) {
  int cb = blockIdx.x;
  int wv = threadIdx.x >> 6, lane = threadIdx.x & 63, lr = lane & 15, lkg = lane >> 4;
  const _Float16* Ab = WaT + ((size_t)(cb * 128 + wv * 32 + lr)) * H_ + lkg * 8;
  for (int i = 0; i < 8; ++i) {
    int n = blockIdx.y * 8 + i;
    const _Float16* Bb = AfT + ((size_t)n * 16 + lr) * H_ + lkg * 8;
    f32x4 acc0 = (f32x4){0, 0, 0, 0}, acc1 = (f32x4){0, 0, 0, 0};
    for (int kk = 0; kk < H_; kk += 32) {
      half8 b = *(const half8*)(Bb + kk);
      half8 a0 = *(const half8*)(Ab + kk);
      half8 a1 = *(const half8*)(Ab + (size_t)16 * H_ + kk);
      acc0 = __builtin_amdgcn_mfma_f32_16x16x32_f16(a0, b, acc0, 0, 0, 0);
      acc1 = __builtin_amdgcn_mfma_f32_16x16x32_f16(a1, b, acc1, 0, 0, 0);
    }
#pragma unroll
    for (int j = 0; j < 4; ++j) {
      G[((size_t)n * FOURH + cb * 128 + wv * 32 + lkg * 4 + j) * 16 + lr] = (_Float16)acc0[j];
      G[((size_t)n * FOURH + cb * 128 + wv * 32 + 16 + lkg * 4 + j) * 16 + lr] = (_Float16)acc1[j];
    }
  }
}

// ---------------- sequential recurrence: 256 blocks x 640 threads ----------------
// r13 body with: nt hints reverted, barrier split into 8 per-rh-group counters,
// S-zeroing made group-local (required once groups may drift).
__global__ __launch_bounds__(640, 3) void seq_kernel(
    const _Float16* __restrict__ Wt, const _Float16* __restrict__ G,
    const float* __restrict__ Afull, const _Float16* __restrict__ Af16,
    const _Float16* __restrict__ x16, const float* __restrict__ bp,
    _Float16* __restrict__ hbuf, float* __restrict__ S,
    float* __restrict__ out, unsigned* __restrict__ bar) {
  __shared__ _Float16 blds[SPB * K3];        // 57,344 B (aliased as acc f32[16][ACCS] post-GEMM)
  __shared__ _Float16 glds[SPB * GLP];       // 82,176 B (G slice, padded stride)
  __shared__ _Float16 htr[SPB][40];          //  1,280 B
  __shared__ float sred[10][16][17];         // 10,880 B
  __shared__ float sc_s[16][16];             //  1,024 B
  float* acclds = (float*)blds;

  const int bid = blockIdx.x, tid = threadIdx.x;
  const int li = (bid & 7) * 32 + (bid >> 3);   // cluster strips per XCD
  const int s = li >> 3, rh = li & 7, n0 = rh * SPB;
  const int w = tid >> 6, lane = tid & 63;
  const int lr = lane & 15, lkg = lane >> 4, lkg8 = lkg * 8;
  const int bswz = (lr & 7) * 8;
  const int en = tid & 15, eq = tid >> 4;       // epilogue: thread owns (sample en, q eq)
  const int ehidx = s * 40 + eq;
  const int emyn = n0 + en;
  unsigned* gbar_p = bar + rh * 16;             // per-group counter, 64 B apart

  // ---- G slice -> LDS once (step-invariant): 16n x 160colp x 16l, padded stride ----
#pragma unroll
  for (int j = 0; j < 8; ++j) {
    int id = tid + j * 640;
    if (id < 5120) {
      int n = id / 320, r = id % 320;
      *(u32x4*)&glds[n * GLP + r * 8] =
          *(const u32x4*)(G + ((size_t)(n0 + n) * FOURH + s * COLS) * 16 + r * 8);
    }
  }

  const _Float16* Ap = Wt + (size_t)(s * COLS + w * 16 + lr) * K3 + lkg8;
  float c_reg;

  // ---- init: h0 = mean_l Af, c0 = h0, scores for step 0 ----
  {
    const f32x4* afp = (const f32x4*)(Afull + ((size_t)emyn * H_ + ehidx) * 16);
    f32x4 a0 = afp[0], a1 = afp[1], a2 = afp[2], a3 = afp[3];
    float sum = 0.f;
#pragma unroll
    for (int j = 0; j < 4; ++j) sum += a0[j] + a1[j] + a2[j] + a3[j];
    float h0 = sum * 0.0625f;
    c_reg = h0;
    htr[en][eq] = (_Float16)h0;
    float pl[16];
#pragma unroll
    for (int j = 0; j < 4; ++j) {
      pl[j] = h0 * a0[j]; pl[4 + j] = h0 * a1[j];
      pl[8 + j] = h0 * a2[j]; pl[12 + j] = h0 * a3[j];
    }
#pragma unroll
    for (int l = 0; l < 16; ++l) {
      pl[l] += __shfl_xor(pl[l], 16);
      pl[l] += __shfl_xor(pl[l], 32);
    }
    if (lane < 16) {
#pragma unroll
      for (int l = 0; l < 16; ++l) sred[w][lane][l] = pl[l];
    }
    __syncthreads();
    if (tid < 256) {
      int n = tid >> 4, l = tid & 15;
      float v = 0.f;
#pragma unroll
      for (int ww = 0; ww < 10; ++ww) v += sred[ww][n][l];
      __hip_atomic_fetch_add(S + (size_t)(n0 + n) * 16 + l, v,
                             __ATOMIC_RELAXED, __HIP_MEMORY_SCOPE_AGENT);
    }
    if (tid < 80) {
      int n = tid / 5, ch = tid % 5;
      u32x4 v = *(const u32x4*)&htr[n][ch * 8];
      sc_store_u4(hbuf + (size_t)(n0 + n) * H_ + s * 40 + ch * 8, v);
    }
    gbar(gbar_p, GRP);
  }

  for (int t = 0; t < T_; ++t) {
    const int par = t & 1;
    // ---- stage h (sc) + x_t -> LDS; scores (sc) via LDS ----
    const _Float16* hsrc = hbuf + ((size_t)par * N_ + n0) * H_;
    u32x4 hv[4];
#pragma unroll
    for (int j = 0; j < 4; ++j) sc_load_u4(hv[j], hsrc + (tid + j * 640) * 8);
    u32x4 svr;
    if (tid < 64)
      sc_load_u4(svr, S + (size_t)(t % 3) * 2048 + (size_t)(n0 + (tid >> 2)) * 16 + (tid & 3) * 4);
    half8 xh[2];
#pragma unroll
    for (int j = 0; j < 2; ++j) {
      int id = tid + j * 640;
      if (id < 1024)
        xh[j] = *(const half8*)(x16 + ((size_t)(n0 + (id >> 6)) * T_ + t) * D_ + (id & 63) * 8);
    }
    vm_wait0();
    __builtin_amdgcn_sched_barrier(0);
#pragma unroll
    for (int j = 0; j < 4; ++j) {
      int i = tid + j * 640;
      int n_l = i / 160, c8 = i % 160;
      *(u32x4*)&blds[((size_t)n_l * 224 + (c8 ^ (n_l & 7))) * 8] = hv[j];
    }
#pragma unroll
    for (int j = 0; j < 2; ++j) {
      int id = tid + j * 640;
      if (id < 1024) {
        int xn = id >> 6, c8 = 160 + (id & 63);
        *(half8*)&blds[((size_t)xn * 224 + (c8 ^ (xn & 7))) * 8] = xh[j];
      }
    }
    if (tid < 64) *(u32x4*)&sc_s[tid >> 2][(tid & 3) * 4] = svr;
    __syncthreads();

    // softmax for this thread's sample
    float wgt[16], m = -1e30f;
#pragma unroll
    for (int l = 0; l < 16; ++l) { wgt[l] = sc_s[en][l] * SCALE; m = fmaxf(m, wgt[l]); }
    float ssum = 0.f;
#pragma unroll
    for (int l = 0; l < 16; ++l) { wgt[l] = __expf(wgt[l] - m); ssum += wgt[l]; }
    float inv = 1.0f / ssum;
    half2_t wh[8];
#pragma unroll
    for (int i = 0; i < 8; ++i) {
      wh[i][0] = (_Float16)(wgt[2 * i] * inv);
      wh[i][1] = (_Float16)(wgt[2 * i + 1] * inv);
    }

    // ---- GEMM: wave w owns 16 cols; depth-8 A double-buffer from L2-resident W ----
    f32x4 acc = (f32x4){0, 0, 0, 0};
    {
      half8 a0[4], a1[4];
#pragma unroll
      for (int j = 0; j < 4; ++j) a0[j] = *(const half8*)(Ap + j * 32);
#pragma unroll
      for (int rep = 0; rep < 6; ++rep) {
        const int base = rep * 256;
#pragma unroll
        for (int j = 0; j < 4; ++j) a1[j] = *(const half8*)(Ap + base + 128 + j * 32);
#pragma unroll
        for (int j = 0; j < 4; ++j) {
          half8 bf = *(const half8*)&blds[(size_t)lr * K3 + ((base + j * 32 + lkg8) ^ bswz)];
          acc = __builtin_amdgcn_mfma_f32_16x16x32_f16(a0[j], bf, acc, 0, 0, 0);
        }
#pragma unroll
        for (int j = 0; j < 4; ++j) a0[j] = *(const half8*)(Ap + base + 256 + j * 32);
#pragma unroll
        for (int j = 0; j < 4; ++j) {
          half8 bf = *(const half8*)&blds[(size_t)lr * K3 + ((base + 128 + j * 32 + lkg8) ^ bswz)];
          acc = __builtin_amdgcn_mfma_f32_16x16x32_f16(a1[j], bf, acc, 0, 0, 0);
        }
      }
#pragma unroll
      for (int j = 0; j < 4; ++j) a1[j] = *(const half8*)(Ap + 1664 + j * 32);
#pragma unroll
      for (int j = 0; j < 4; ++j) {
        half8 bf = *(const half8*)&blds[(size_t)lr * K3 + ((1536 + j * 32 + lkg8) ^ bswz)];
        acc = __builtin_amdgcn_mfma_f32_16x16x32_f16(a0[j], bf, acc, 0, 0, 0);
      }
#pragma unroll
      for (int j = 0; j < 4; ++j) {
        half8 bf = *(const half8*)&blds[(size_t)lr * K3 + ((1664 + j * 32 + lkg8) ^ bswz)];
        acc = __builtin_amdgcn_mfma_f32_16x16x32_f16(a1[j], bf, acc, 0, 0, 0);
      }
    }
    __syncthreads();                       // B consumed; alias blds as acc transpose
    // D[row=(lkg*4+j)=gatecol_local, col=lr=sample] -> acclds[sample][gatecol]
#pragma unroll
    for (int j = 0; j < 4; ++j)
      acclds[lr * ACCS + w * 16 + lkg * 4 + j] = acc[j];
    __syncthreads();

    // ---- epilogue: thread (en, eq) -> 4 gates, c/h update, out, score partials ----
    {
      const float* av4 = acclds + en * ACCS + eq * 4;
      const unsigned* gp32 = (const unsigned*)(glds + en * GLP + eq * 64);
      f32x4 bb = *(const f32x4*)(bp + s * COLS + eq * 4);
      float av[4];
#pragma unroll
      for (int g4 = 0; g4 < 4; ++g4) {
        float gd = 0.f;
#pragma unroll
        for (int i = 0; i < 8; ++i)
          gd = __builtin_amdgcn_fdot2(__builtin_bit_cast(half2_t, gp32[g4 * 8 + i]), wh[i], gd, false);
        av[g4] = av4[g4] + gd + bb[g4];
      }
      float cn = sigf(av[1]) * c_reg + sigf(av[0]) * tanhfast(av[3]);
      c_reg = cn;
      float hn = sigf(av[2]) * tanhfast(cn);
      out[((size_t)emyn * T_ + t) * H_ + ehidx] = hn;

      if (t < T_ - 1) {
        const half8* af8 = (const half8*)(Af16 + ((size_t)emyn * H_ + ehidx) * 16);
        half8 v0 = af8[0], v1 = af8[1];
        float pl[16];
#pragma unroll
        for (int l = 0; l < 8; ++l) { pl[l] = hn * (float)v0[l]; pl[8 + l] = hn * (float)v1[l]; }
        htr[en][eq] = (_Float16)hn;
#pragma unroll
        for (int l = 0; l < 16; ++l) {
          pl[l] += __shfl_xor(pl[l], 16);
          pl[l] += __shfl_xor(pl[l], 32);
        }
        if (lane < 16) {
#pragma unroll
          for (int l = 0; l < 16; ++l) sred[w][lane][l] = pl[l];
        }
        __syncthreads();
        if (tid < 256) {
          int n = tid >> 4, l = tid & 15;
          float v = 0.f;
#pragma unroll
          for (int ww = 0; ww < 10; ++ww) v += sred[ww][n][l];
          __hip_atomic_fetch_add(S + (size_t)((t + 1) % 3) * 2048 + (size_t)(n0 + n) * 16 + l, v,
                                 __ATOMIC_RELAXED, __HIP_MEMORY_SCOPE_AGENT);
        }
        // zero THIS GROUP's 256-word slice of S[(t+2)%3]: strip s zeroes 8 words
        if (tid < 8)
          sc_store_u1((unsigned*)(S + (size_t)((t + 2) % 3) * 2048 + (size_t)n0 * 16) + s * 8 + tid,
                      0u);
        if (tid < 80) {
          int n = tid / 5, ch = tid % 5;
          u32x4 v = *(const u32x4*)&htr[n][ch * 8];
          sc_store_u4(hbuf + ((size_t)((par ^ 1) * N_) + n0 + n) * H_ + s * 40 + ch * 8, v);
        }
        gbar(gbar_p, (unsigned)(t + 2) * GRP);
      }
    }
  }
}

// ---------------- launch ----------------
extern "C" void kernel_launch(void* const* d_in, const int* in_sizes, int n_in,
                              void* d_out, int out_size, void* d_ws, size_t ws_size,
                              hipStream_t stream) {
  const float* x  = (const float*)d_in[0];
  const float* A  = (const float*)d_in[1];
  const float* Wx = (const float*)d_in[2];
  const float* Wh = (const float*)d_in[3];
  const float* Wa = (const float*)d_in[4];
  const float* b  = (const float*)d_in[5];
  float* out = (float*)d_out;
  char* ws = (char*)d_ws;

  _Float16* Xreg = (_Float16*)(ws);                 // 18,350,080 (WaT then WcatT)
  _Float16* x16r = (_Float16*)(ws + 18350080);      //  8,388,608 (first holds AfT 5,242,880)
  _Float16* G    = (_Float16*)(ws + 26738688);      // 20,971,520
  _Float16* Af16 = (_Float16*)(ws + 47710208);      //  5,242,880
  _Float16* hbuf = (_Float16*)(ws + 52953088);      //    655,360
  float*    S    = (float*)(ws + 53608448);         //     24,576
  unsigned* bar  = (unsigned*)(ws + 53633024);      //        512 (8 counters, 64B apart)
  float*    bpm  = (float*)(ws + 53633536);         //     20,480  -> total ~53.65 MB

  (void)hipMemsetAsync(S, 0, 24576 + 512, stream);  // S + bar
  // phase 1: WaT into Xreg; AfT into x16 region; G = Af^T @ Wattn
  trans_w<<<dim3(160, 5), 256, 0, stream>>>(Wa, Xreg, H_, 0);
  prep_af<<<N_, 256, 0, stream>>>(A, x16r, Af16);
  gemm_G<<<dim3(40, 16), 256, 0, stream>>>(Xreg, x16r, G);
  // phase 2: overwrite Xreg with WcatT = [Wh; Wx]; overwrite AfT region with x16
  trans_w<<<dim3(160, 5), 256, 0, stream>>>(Wh, Xreg, K3, 0);
  trans_w<<<dim3(160, 2), 256, 0, stream>>>(Wx, Xreg, K3, H_);
  cvt_f16<<<2048, 256, 0, stream>>>(x, x16r, N_ * T_ * D_);
  prep_b<<<20, 256, 0, stream>>>(b, bpm);

  seq_kernel<<<dim3(NB), dim3(640), 0, stream>>>(Xreg, G, A, Af16, x16r, bpm, hbuf, S, out, bar);
}